// Round 3
// baseline (125.910 us; speedup 1.0000x reference)
//
#include <hip/hip_runtime.h>

namespace {

constexpr int kB = 4;
constexpr int kT = 512;
constexpr int kH = 256;

__device__ __forceinline__ float rcpf(float x) {
  return __builtin_amdgcn_rcpf(x);
}

// ---------------- k0: transpose W1,W2 (H x H) into Wt ----------------
__global__ __launch_bounds__(256) void transpose_w_kernel(
    const float* __restrict__ W1, const float* __restrict__ W2,
    float* __restrict__ Wt1, float* __restrict__ Wt2) {
  __shared__ float tile[32][33];
  const float* Win = (blockIdx.z == 0) ? W1 : W2;
  float* Wout = (blockIdx.z == 0) ? Wt1 : Wt2;
  const int jo = blockIdx.x * 32, ho = blockIdx.y * 32;
  const int c = threadIdx.x & 31, r0 = threadIdx.x >> 5;
#pragma unroll
  for (int p = 0; p < 4; ++p)
    tile[r0 + 8 * p][c] = Win[(size_t)(ho + r0 + 8 * p) * kH + jo + c];
  __syncthreads();
#pragma unroll
  for (int p = 0; p < 4; ++p)
    Wout[(size_t)(jo + r0 + 8 * p) * kH + ho + c] = tile[c][r0 + 8 * p];
}

// ---------------- k1: projections, exp, TRANSPOSED layout ----------------
// y==0: EQt[b][h][t] = exp(2*q[t][h]);  y==1: EKt[b][h][s] = exp(2*k[s][h])
__global__ __launch_bounds__(256) void proj_kernel(
    const float* __restrict__ X, const float* __restrict__ Wt1,
    const float* __restrict__ Wt2, float* __restrict__ EQt,
    float* __restrict__ EKt) {
  const int tid = threadIdx.x;  // h
  const int row0 = blockIdx.x * 8;
  const float* Wt = (blockIdx.y == 0) ? Wt1 : Wt2;
  float* dst = (blockIdx.y == 0) ? EQt : EKt;

  float acc[8];
#pragma unroll
  for (int i = 0; i < 8; ++i) acc[i] = 0.0f;

  for (int j0 = 0; j0 < kH; j0 += 8) {
    float wv[8];
#pragma unroll
    for (int u = 0; u < 8; ++u) wv[u] = Wt[(size_t)(j0 + u) * kH + tid];
#pragma unroll
    for (int i = 0; i < 8; ++i) {
      const float* xr = X + (size_t)(row0 + i) * kH;  // block-uniform -> s_load
#pragma unroll
      for (int u = 0; u < 8; ++u)
        acc[i] = __builtin_fmaf(xr[j0 + u], wv[u], acc[i]);
    }
  }
  // thread owns column h=tid for 8 consecutive rows -> contiguous in [h][row]
  const int bb = row0 >> 9, r0 = row0 & (kT - 1);
  float* out = dst + ((size_t)(bb * kH + tid)) * kT + r0;
  float4 lo = {__expf(2.0f * acc[0]), __expf(2.0f * acc[1]),
               __expf(2.0f * acc[2]), __expf(2.0f * acc[3])};
  float4 hi = {__expf(2.0f * acc[4]), __expf(2.0f * acc[5]),
               __expf(2.0f * acc[6]), __expf(2.0f * acc[7])};
  *reinterpret_cast<float4*>(out) = lo;
  *reinterpret_cast<float4*>(out + 4) = hi;
}

// ---------------- k2: register-tiled causal score kernel ----------------
// score[t][s] = vsum - 2 * sum_h v[h] * rcp(EQt[h][t]*EKt[h][s] + 1)
// One 16x16 tile per wave; 2t x 2s per lane; triangular tile enumeration.
__global__ __launch_bounds__(256) void score_kernel(
    const float* __restrict__ EQt, const float* __restrict__ EKt,
    const float* __restrict__ v, float* __restrict__ Sc) {
  const int b = blockIdx.y;
  const int w = threadIdx.x >> 6;
  const int lane = threadIdx.x & 63;
  const int tIdx = blockIdx.x * 4 + w;  // 0..527 causal tile index

  // triangular decode (wave-uniform scalar math)
  int ti = (int)((__builtin_sqrtf(8.0f * (float)tIdx + 1.0f) - 1.0f) * 0.5f);
  while ((ti + 1) * (ti + 2) / 2 <= tIdx) ++ti;
  while (ti * (ti + 1) / 2 > tIdx) --ti;
  const int si = tIdx - ti * (ti + 1) / 2;
  const int t0 = ti * 16, s0 = si * 16;

  const int ty = lane >> 3, sx = lane & 7;
  const float* eqp = EQt + ((size_t)b * kH) * kT + t0 + 2 * ty;
  const float* ekp = EKt + ((size_t)b * kH) * kT + s0 + 2 * sx;

  float a00 = 0.f, a01 = 0.f, a10 = 0.f, a11 = 0.f;  // h-even bank
  float b00 = 0.f, b01 = 0.f, b10 = 0.f, b11 = 0.f;  // h-odd bank

#pragma unroll 4
  for (int h = 0; h < kH; h += 2) {
    const float2 eqA = *reinterpret_cast<const float2*>(eqp + (size_t)h * kT);
    const float2 ekA = *reinterpret_cast<const float2*>(ekp + (size_t)h * kT);
    const float2 eqB =
        *reinterpret_cast<const float2*>(eqp + (size_t)h * kT + kT);
    const float2 ekB =
        *reinterpret_cast<const float2*>(ekp + (size_t)h * kT + kT);
    const float vA = v[h];      // loop-uniform -> s_load
    const float vB = v[h + 1];
    a00 = __builtin_fmaf(vA, rcpf(__builtin_fmaf(eqA.x, ekA.x, 1.0f)), a00);
    a01 = __builtin_fmaf(vA, rcpf(__builtin_fmaf(eqA.x, ekA.y, 1.0f)), a01);
    a10 = __builtin_fmaf(vA, rcpf(__builtin_fmaf(eqA.y, ekA.x, 1.0f)), a10);
    a11 = __builtin_fmaf(vA, rcpf(__builtin_fmaf(eqA.y, ekA.y, 1.0f)), a11);
    b00 = __builtin_fmaf(vB, rcpf(__builtin_fmaf(eqB.x, ekB.x, 1.0f)), b00);
    b01 = __builtin_fmaf(vB, rcpf(__builtin_fmaf(eqB.x, ekB.y, 1.0f)), b01);
    b10 = __builtin_fmaf(vB, rcpf(__builtin_fmaf(eqB.y, ekB.x, 1.0f)), b10);
    b11 = __builtin_fmaf(vB, rcpf(__builtin_fmaf(eqB.y, ekB.y, 1.0f)), b11);
  }

  // vsum = sum_h v[h]
  float vv = v[lane] + v[lane + 64] + v[lane + 128] + v[lane + 192];
#pragma unroll
  for (int off = 32; off > 0; off >>= 1) vv += __shfl_xor(vv, off, 64);

  const float r00 = a00 + b00, r01 = a01 + b01;
  const float r10 = a10 + b10, r11 = a11 + b11;
  float2 row0v = {__builtin_fmaf(-2.0f, r00, vv),
                  __builtin_fmaf(-2.0f, r01, vv)};
  float2 row1v = {__builtin_fmaf(-2.0f, r10, vv),
                  __builtin_fmaf(-2.0f, r11, vv)};
  float* so = Sc + ((size_t)(b * kT + t0 + 2 * ty)) * kT + s0 + 2 * sx;
  *reinterpret_cast<float2*>(so) = row0v;
  *reinterpret_cast<float2*>(so + kT) = row1v;
}

// ---------------- k3: softmax + weights + context ----------------
// wsc aliases the score buffer: read scores, overwrite with weights.
__global__ __launch_bounds__(512, 4) void attn2_kernel(
    const float* __restrict__ X, float* wsc, float* __restrict__ ctx) {
  __shared__ __align__(16) float sc[4][kT];
  __shared__ float redm[8][4];

  const int g = blockIdx.x;   // 0..127
  const int b = blockIdx.y;   // 0..3
  const int tid = threadIdx.x;
  const int tt0 = 511 - g, tt1 = 256 + g, tt2 = 255 - g, tt3 = g;
  const int tt[4] = {tt0, tt1, tt2, tt3};

  float p[4];
#pragma unroll
  for (int k = 0; k < 4; ++k) {
    const float s = wsc[((size_t)(b * kT + tt[k])) * kT + tid];
    p[k] = (tid <= tt[k]) ? __expf(s) : 0.0f;
    float l = p[k];
#pragma unroll
    for (int off = 32; off > 0; off >>= 1) l += __shfl_xor(l, off, 64);
    if ((tid & 63) == 0) redm[tid >> 6][k] = l;
  }
  __syncthreads();
#pragma unroll
  for (int k = 0; k < 4; ++k) {
    float sum = 0.f;
#pragma unroll
    for (int w = 0; w < 8; ++w) sum += redm[w][k];
    const float wgt = p[k] * rcpf(sum);
    wsc[((size_t)(b * kT + tt[k])) * kT + tid] = wgt;
    sc[k][tid] = wgt;
  }
  __syncthreads();

  // context: halves {rows tt0,tt3} / {rows tt1,tt2}, thread owns h
  const int half = tid >> 8;
  const int h = tid & (kH - 1);
  const int longT = half ? tt1 : tt0;
  const int shortT = half ? tt2 : tt3;
  const float* wL = half ? &sc[1][0] : &sc[0][0];
  const float* wS = half ? &sc[2][0] : &sc[3][0];
  const float* Xb = X + ((size_t)b * kT) * kH + h;

  float aL = 0.f, aS = 0.f;
  int si = 0;
#pragma unroll 4
  for (; si <= shortT; ++si) {
    const float x = Xb[(size_t)si * kH];
    aL = __builtin_fmaf(wL[si], x, aL);
    aS = __builtin_fmaf(wS[si], x, aS);
  }
#pragma unroll 4
  for (; si <= longT; ++si) {
    const float x = Xb[(size_t)si * kH];
    aL = __builtin_fmaf(wL[si], x, aL);
  }
  ctx[(size_t)(b * kT + longT) * kH + h] = aL;
  ctx[(size_t)(b * kT + shortT) * kH + h] = aS;
}

}  // namespace

extern "C" void kernel_launch(void* const* d_in, const int* in_sizes, int n_in,
                              void* d_out, int out_size, void* d_ws,
                              size_t ws_size, hipStream_t stream) {
  const float* X = (const float*)d_in[0];
  const float* W1 = (const float*)d_in[1];
  const float* W2 = (const float*)d_in[2];
  const float* v = (const float*)d_in[3];

  float* ctx = (float*)d_out;                   // [B*T][H]  2 MB
  float* wout = ctx + (size_t)kB * kT * kH;     // [B*T][T]  4 MB
  // scratch inside wout (each stage fully consumed before overwrite):
  float* Wt1 = wout;                            // 256 KB  (k0 -> k1)
  float* Wt2 = wout + (size_t)kH * kH;          // 256 KB  (k0 -> k1)
  float* Sc = wout;                             // 4 MB    (k2 -> k3)
  float* EQt = (float*)d_ws;                    // [B][H][T]  2 MB
  float* EKt = EQt + (size_t)kB * kH * kT;      // [B][H][T]  2 MB

  transpose_w_kernel<<<dim3(8, 8, 2), 256, 0, stream>>>(W1, W2, Wt1, Wt2);
  proj_kernel<<<dim3(kB * kT / 8, 2), 256, 0, stream>>>(X, Wt1, Wt2, EQt, EKt);
  score_kernel<<<dim3(132, kB), 256, 0, stream>>>(EQt, EKt, v, Sc);
  attn2_kernel<<<dim3(kT / 4, kB), 512, 0, stream>>>(X, Sc, ctx);
}

// Round 4
// 96.206 us; speedup vs baseline: 1.3088x; 1.3088x over previous
//
#include <hip/hip_runtime.h>

namespace {

constexpr int kB = 4;
constexpr int kT = 512;
constexpr int kH = 256;

__device__ __forceinline__ float rcpf(float x) {
  return __builtin_amdgcn_rcpf(x);
}

// ---------------- k0: transpose W1,W2 (H x H) into Wt ----------------
__global__ __launch_bounds__(256) void transpose_w_kernel(
    const float* __restrict__ W1, const float* __restrict__ W2,
    float* __restrict__ Wt1, float* __restrict__ Wt2) {
  __shared__ float tile[32][33];
  const float* Win = (blockIdx.z == 0) ? W1 : W2;
  float* Wout = (blockIdx.z == 0) ? Wt1 : Wt2;
  const int jo = blockIdx.x * 32, ho = blockIdx.y * 32;
  const int c = threadIdx.x & 31, r0 = threadIdx.x >> 5;
#pragma unroll
  for (int p = 0; p < 4; ++p)
    tile[r0 + 8 * p][c] = Win[(size_t)(ho + r0 + 8 * p) * kH + jo + c];
  __syncthreads();
#pragma unroll
  for (int p = 0; p < 4; ++p)
    Wout[(size_t)(jo + r0 + 8 * p) * kH + ho + c] = tile[c][r0 + 8 * p];
}

// ---------------- k1: projections, exp, TRANSPOSED layout ----------------
// y==0: EQt[b][h][t] = exp(2*q[t][h]);  y==1: EKt[b][h][s] = exp(2*k[s][h])
__global__ __launch_bounds__(256) void proj_kernel(
    const float* __restrict__ X, const float* __restrict__ Wt1,
    const float* __restrict__ Wt2, float* __restrict__ EQt,
    float* __restrict__ EKt) {
  const int tid = threadIdx.x;  // h
  const int row0 = blockIdx.x * 8;
  const float* Wt = (blockIdx.y == 0) ? Wt1 : Wt2;
  float* dst = (blockIdx.y == 0) ? EQt : EKt;

  float acc[8];
#pragma unroll
  for (int i = 0; i < 8; ++i) acc[i] = 0.0f;

  for (int j0 = 0; j0 < kH; j0 += 8) {
    float wv[8];
#pragma unroll
    for (int u = 0; u < 8; ++u) wv[u] = Wt[(size_t)(j0 + u) * kH + tid];
#pragma unroll
    for (int i = 0; i < 8; ++i) {
      const float* xr = X + (size_t)(row0 + i) * kH;  // block-uniform -> s_load
#pragma unroll
      for (int u = 0; u < 8; ++u)
        acc[i] = __builtin_fmaf(xr[j0 + u], wv[u], acc[i]);
    }
  }
  const int bb = row0 >> 9, r0 = row0 & (kT - 1);
  float* out = dst + ((size_t)(bb * kH + tid)) * kT + r0;
  float4 lo = {__expf(2.0f * acc[0]), __expf(2.0f * acc[1]),
               __expf(2.0f * acc[2]), __expf(2.0f * acc[3])};
  float4 hi = {__expf(2.0f * acc[4]), __expf(2.0f * acc[5]),
               __expf(2.0f * acc[6]), __expf(2.0f * acc[7])};
  *reinterpret_cast<float4*>(out) = lo;
  *reinterpret_cast<float4*>(out + 4) = hi;
}

// ---------------- k2: register-tiled causal score kernel ----------------
// score[t][s] = vsum - 2 * sum_h v[h] * rcp(EQt[h][t]*EKt[h][s] + 1)
// One 16x16 tile per wave; 2t x 2s per lane; XCD-pinned batches;
// 4-bank rolling register prefetch (banks load ~7 compute-steps ahead).
__global__ __launch_bounds__(256) void score_kernel(
    const float* __restrict__ EQt, const float* __restrict__ EKt,
    const float* __restrict__ v, float* __restrict__ Sc) {
  const int w = threadIdx.x >> 6;
  const int lane = threadIdx.x & 63;
  // XCD pinning: 8 XCDs, 2 per batch; each XCD streams only its batch's 2MB.
  const int xcd = blockIdx.x & 7;
  const int b = xcd >> 1;
  const int tIdx = (xcd & 1) * 264 + (blockIdx.x >> 3) * 4 + w;  // 0..527

  // triangular decode (wave-uniform)
  int ti = (int)((__builtin_sqrtf(8.0f * (float)tIdx + 1.0f) - 1.0f) * 0.5f);
  while ((ti + 1) * (ti + 2) / 2 <= tIdx) ++ti;
  while (ti * (ti + 1) / 2 > tIdx) --ti;
  const int si = tIdx - ti * (ti + 1) / 2;
  const int t0 = ti * 16, s0 = si * 16;

  const int ty = lane >> 3, sx = lane & 7;
  const float* eqp = EQt + ((size_t)b * kH) * kT + t0 + 2 * ty;
  const float* ekp = EKt + ((size_t)b * kH) * kT + s0 + 2 * sx;

  float ac0 = 0.f, ac1 = 0.f, ac2 = 0.f, ac3 = 0.f;  // h-even
  float ac4 = 0.f, ac5 = 0.f, ac6 = 0.f, ac7 = 0.f;  // h-odd

  float2 qA0, kA0, qB0, kB0;
  float2 qA1, kA1, qB1, kB1;
  float2 qA2, kA2, qB2, kB2;
  float2 qA3, kA3, qB3, kB3;

#define LOADB(B, H)                                                       \
  qA##B = *reinterpret_cast<const float2*>(eqp + (size_t)(H)*kT);         \
  kA##B = *reinterpret_cast<const float2*>(ekp + (size_t)(H)*kT);         \
  qB##B = *reinterpret_cast<const float2*>(eqp + (size_t)((H) + 1) * kT); \
  kB##B = *reinterpret_cast<const float2*>(ekp + (size_t)((H) + 1) * kT);

#define COMPB(B, H)                                                            \
  {                                                                            \
    const float vA = v[(H)];                                                   \
    const float vB = v[(H) + 1];                                               \
    ac0 = __builtin_fmaf(vA, rcpf(__builtin_fmaf(qA##B.x, kA##B.x, 1.0f)), ac0); \
    ac1 = __builtin_fmaf(vA, rcpf(__builtin_fmaf(qA##B.x, kA##B.y, 1.0f)), ac1); \
    ac2 = __builtin_fmaf(vA, rcpf(__builtin_fmaf(qA##B.y, kA##B.x, 1.0f)), ac2); \
    ac3 = __builtin_fmaf(vA, rcpf(__builtin_fmaf(qA##B.y, kA##B.y, 1.0f)), ac3); \
    ac4 = __builtin_fmaf(vB, rcpf(__builtin_fmaf(qB##B.x, kB##B.x, 1.0f)), ac4); \
    ac5 = __builtin_fmaf(vB, rcpf(__builtin_fmaf(qB##B.x, kB##B.y, 1.0f)), ac5); \
    ac6 = __builtin_fmaf(vB, rcpf(__builtin_fmaf(qB##B.y, kB##B.x, 1.0f)), ac6); \
    ac7 = __builtin_fmaf(vB, rcpf(__builtin_fmaf(qB##B.y, kB##B.y, 1.0f)), ac7); \
  }

  LOADB(0, 0)
  LOADB(1, 2)
  LOADB(2, 4)
  LOADB(3, 6)

  int h = 0;
  for (; h < kH - 8; h += 8) {
    COMPB(0, h)
    LOADB(0, h + 8)
    COMPB(1, h + 2)
    LOADB(1, h + 10)
    COMPB(2, h + 4)
    LOADB(2, h + 12)
    COMPB(3, h + 6)
    LOADB(3, h + 14)
  }
  COMPB(0, h)
  COMPB(1, h + 2)
  COMPB(2, h + 4)
  COMPB(3, h + 6)

#undef LOADB
#undef COMPB

  // vsum = sum_h v[h]
  float vv = v[lane] + v[lane + 64] + v[lane + 128] + v[lane + 192];
#pragma unroll
  for (int off = 32; off > 0; off >>= 1) vv += __shfl_xor(vv, off, 64);

  float2 row0v = {__builtin_fmaf(-2.0f, ac0 + ac4, vv),
                  __builtin_fmaf(-2.0f, ac1 + ac5, vv)};
  float2 row1v = {__builtin_fmaf(-2.0f, ac2 + ac6, vv),
                  __builtin_fmaf(-2.0f, ac3 + ac7, vv)};
  float* so = Sc + ((size_t)(b * kT + t0 + 2 * ty)) * kT + s0 + 2 * sx;
  *reinterpret_cast<float2*>(so) = row0v;
  *reinterpret_cast<float2*>(so + kT) = row1v;
}

// ---------------- k3: softmax + weights + context ----------------
// wsc aliases the score buffer: read scores, overwrite with weights.
__global__ __launch_bounds__(512, 4) void attn2_kernel(
    const float* __restrict__ X, float* wsc, float* __restrict__ ctx) {
  __shared__ __align__(16) float sc[4][kT];
  __shared__ float redm[8][4];

  // XCD pinning: b = xcd>>1 -> X[b] (1MB) stays L2-resident per XCD.
  const int id = blockIdx.x;
  const int xcd = id & 7;
  const int b = xcd >> 1;
  const int g = (xcd & 1) * 64 + (id >> 3);  // 0..127
  const int tid = threadIdx.x;
  const int tt0 = 511 - g, tt1 = 256 + g, tt2 = 255 - g, tt3 = g;
  const int tt[4] = {tt0, tt1, tt2, tt3};

  float p[4];
#pragma unroll
  for (int k = 0; k < 4; ++k) {
    const float s = wsc[((size_t)(b * kT + tt[k])) * kT + tid];
    p[k] = (tid <= tt[k]) ? __expf(s) : 0.0f;
    float l = p[k];
#pragma unroll
    for (int off = 32; off > 0; off >>= 1) l += __shfl_xor(l, off, 64);
    if ((tid & 63) == 0) redm[tid >> 6][k] = l;
  }
  __syncthreads();
#pragma unroll
  for (int k = 0; k < 4; ++k) {
    float sum = 0.f;
#pragma unroll
    for (int w = 0; w < 8; ++w) sum += redm[w][k];
    const float wgt = p[k] * rcpf(sum);
    wsc[((size_t)(b * kT + tt[k])) * kT + tid] = wgt;
    sc[k][tid] = wgt;
  }
  __syncthreads();

  // context: halves {rows tt0,tt3} / {rows tt1,tt2}, thread owns h
  const int half = tid >> 8;
  const int h = tid & (kH - 1);
  const int longT = half ? tt1 : tt0;
  const int shortT = half ? tt2 : tt3;
  const float* wL = half ? &sc[1][0] : &sc[0][0];
  const float* wS = half ? &sc[2][0] : &sc[3][0];
  const float* Xb = X + ((size_t)b * kT) * kH + h;

  float aL = 0.f, aS = 0.f;
  int si = 0;
#pragma unroll 4
  for (; si <= shortT; ++si) {
    const float x = Xb[(size_t)si * kH];
    aL = __builtin_fmaf(wL[si], x, aL);
    aS = __builtin_fmaf(wS[si], x, aS);
  }
#pragma unroll 4
  for (; si <= longT; ++si) {
    const float x = Xb[(size_t)si * kH];
    aL = __builtin_fmaf(wL[si], x, aL);
  }
  ctx[(size_t)(b * kT + longT) * kH + h] = aL;
  ctx[(size_t)(b * kT + shortT) * kH + h] = aS;
}

}  // namespace

extern "C" void kernel_launch(void* const* d_in, const int* in_sizes, int n_in,
                              void* d_out, int out_size, void* d_ws,
                              size_t ws_size, hipStream_t stream) {
  const float* X = (const float*)d_in[0];
  const float* W1 = (const float*)d_in[1];
  const float* W2 = (const float*)d_in[2];
  const float* v = (const float*)d_in[3];

  float* ctx = (float*)d_out;                   // [B*T][H]  2 MB
  float* wout = ctx + (size_t)kB * kT * kH;     // [B*T][T]  4 MB
  // scratch inside wout (each stage fully consumed before overwrite):
  float* Wt1 = wout;                            // 256 KB  (k0 -> k1)
  float* Wt2 = wout + (size_t)kH * kH;          // 256 KB  (k0 -> k1)
  float* Sc = wout;                             // 4 MB    (k2 -> k3)
  float* EQt = (float*)d_ws;                    // [B][H][T]  2 MB
  float* EKt = EQt + (size_t)kB * kH * kT;      // [B][H][T]  2 MB

  transpose_w_kernel<<<dim3(8, 8, 2), 256, 0, stream>>>(W1, W2, Wt1, Wt2);
  proj_kernel<<<dim3(kB * kT / 8, 2), 256, 0, stream>>>(X, Wt1, Wt2, EQt, EKt);
  score_kernel<<<528, 256, 0, stream>>>(EQt, EKt, v, Sc);
  attn2_kernel<<<512, 512, 0, stream>>>(X, Sc, ctx);
}

// Round 5
// 78.395 us; speedup vs baseline: 1.6061x; 1.2272x over previous
//
#include <hip/hip_runtime.h>

namespace {

constexpr int kB = 4;
constexpr int kT = 512;
constexpr int kH = 256;

__device__ __forceinline__ float rcpf(float x) {
  return __builtin_amdgcn_rcpf(x);
}

// ---------------- k0: transpose W1,W2 (H x H) into Wt ----------------
__global__ __launch_bounds__(256) void transpose_w_kernel(
    const float* __restrict__ W1, const float* __restrict__ W2,
    float* __restrict__ Wt1, float* __restrict__ Wt2) {
  __shared__ float tile[32][33];
  const float* Win = (blockIdx.z == 0) ? W1 : W2;
  float* Wout = (blockIdx.z == 0) ? Wt1 : Wt2;
  const int jo = blockIdx.x * 32, ho = blockIdx.y * 32;
  const int c = threadIdx.x & 31, r0 = threadIdx.x >> 5;
#pragma unroll
  for (int p = 0; p < 4; ++p)
    tile[r0 + 8 * p][c] = Win[(size_t)(ho + r0 + 8 * p) * kH + jo + c];
  __syncthreads();
#pragma unroll
  for (int p = 0; p < 4; ++p)
    Wout[(size_t)(jo + r0 + 8 * p) * kH + ho + c] = tile[c][r0 + 8 * p];
}

// ---------------- k1: projections, exp, TRANSPOSED layout ----------------
// y==0: EQt[b][h][t] = exp(2*q[t][h]);  y==1: EKt[b][h][s] = exp(2*k[s][h])
__global__ __launch_bounds__(256) void proj_kernel(
    const float* __restrict__ X, const float* __restrict__ Wt1,
    const float* __restrict__ Wt2, float* __restrict__ EQt,
    float* __restrict__ EKt) {
  const int tid = threadIdx.x;  // h
  const int row0 = blockIdx.x * 8;
  const float* Wt = (blockIdx.y == 0) ? Wt1 : Wt2;
  float* dst = (blockIdx.y == 0) ? EQt : EKt;

  float acc[8];
#pragma unroll
  for (int i = 0; i < 8; ++i) acc[i] = 0.0f;

  for (int j0 = 0; j0 < kH; j0 += 8) {
    float wv[8];
#pragma unroll
    for (int u = 0; u < 8; ++u) wv[u] = Wt[(size_t)(j0 + u) * kH + tid];
#pragma unroll
    for (int i = 0; i < 8; ++i) {
      const float* xr = X + (size_t)(row0 + i) * kH;  // block-uniform -> s_load
#pragma unroll
      for (int u = 0; u < 8; ++u)
        acc[i] = __builtin_fmaf(xr[j0 + u], wv[u], acc[i]);
    }
  }
  const int bb = row0 >> 9, r0 = row0 & (kT - 1);
  float* out = dst + ((size_t)(bb * kH + tid)) * kT + r0;
  float4 lo = {__expf(2.0f * acc[0]), __expf(2.0f * acc[1]),
               __expf(2.0f * acc[2]), __expf(2.0f * acc[3])};
  float4 hi = {__expf(2.0f * acc[4]), __expf(2.0f * acc[5]),
               __expf(2.0f * acc[6]), __expf(2.0f * acc[7])};
  *reinterpret_cast<float4*>(out) = lo;
  *reinterpret_cast<float4*>(out + 4) = hi;
}

// ---------------- k2: LDS double-buffered causal score kernel ----------------
// score[t][s] = vsum - 2 * sum_h v[h] * rcp(EQt[h][t]*EKt[h][s] + 1)
// 32x32 tile per 256-thread block (4 waves x 16x16). 2-phase pipeline:
// global_load_lds stages next 32-h chunk while computing current from LDS.
__global__ __launch_bounds__(256) void score_kernel(
    const float* __restrict__ EQt, const float* __restrict__ EKt,
    const float* __restrict__ v, float* __restrict__ Sc) {
  __shared__ __align__(16) float eqs[2][32 * 32];  // [buf][h*32 + t] 8KB
  __shared__ __align__(16) float eks[2][32 * 32];  // [buf][h*32 + s] 8KB

  const int tid = threadIdx.x;
  const int w = tid >> 6, lane = tid & 63;
  // XCD pinning: 8 XCDs, 2 per batch.
  const int blk = blockIdx.x;
  const int xcd = blk & 7;
  const int b = xcd >> 1;
  const int tIdx = (xcd & 1) * 68 + (blk >> 3);  // 0..135 causal 32x32 tiles

  // triangular decode (wave-uniform)
  int ti = (int)((__builtin_sqrtf(8.0f * (float)tIdx + 1.0f) - 1.0f) * 0.5f);
  while ((ti + 1) * (ti + 2) / 2 <= tIdx) ++ti;
  while (ti * (ti + 1) / 2 > tIdx) --ti;
  const int si = tIdx - ti * (ti + 1) / 2;
  const int t0 = ti * 32, s0 = si * 32;

  // staging: wave w stages h-rows [w*8, w*8+8) of each 32-h chunk;
  // lane layout matches global_load_lds's base+lane*16 LDS write pattern.
  const int hoff = w * 8 + (lane >> 3);
  const int coff = (lane & 7) * 4;
  const float* gq = EQt + ((size_t)(b * kH + hoff) * kT) + t0 + coff;
  const float* gk = EKt + ((size_t)(b * kH + hoff) * kT) + s0 + coff;
  float* lqw = &eqs[0][0] + w * 256;  // wave-uniform LDS dest base
  float* lkw = &eks[0][0] + w * 256;

#define STAGE(buf, c)                                                        \
  {                                                                          \
    const size_t go = (size_t)(c) * 32 * kT;                                 \
    __builtin_amdgcn_global_load_lds(                                        \
        (const __attribute__((address_space(1))) void*)(gq + go),            \
        (__attribute__((address_space(3))) void*)(lqw + (buf)*1024), 16, 0,  \
        0);                                                                  \
    __builtin_amdgcn_global_load_lds(                                        \
        (const __attribute__((address_space(1))) void*)(gk + go),            \
        (__attribute__((address_space(3))) void*)(lkw + (buf)*1024), 16, 0,  \
        0);                                                                  \
  }

  // compute sub-tile coordinates
  const int wt = w >> 1, ws = w & 1;
  const int tq = wt * 16 + 2 * (lane >> 3);
  const int sk = ws * 16 + 2 * (lane & 7);

  float ac0 = 0.f, ac1 = 0.f, ac2 = 0.f, ac3 = 0.f;  // h-even
  float ac4 = 0.f, ac5 = 0.f, ac6 = 0.f, ac7 = 0.f;  // h-odd

  STAGE(0, 0)
  asm volatile("s_waitcnt vmcnt(0)" ::: "memory");
  __syncthreads();

#pragma unroll 1
  for (int c = 0; c < 8; ++c) {
    if (c < 7) STAGE((c + 1) & 1, c + 1)
    const int boff = (c & 1) * 1024;
    const float* vp = v + c * 32;  // uniform -> s_load
#pragma unroll
    for (int h = 0; h < 32; h += 2) {
      const float2 qA = *reinterpret_cast<const float2*>(&eqs[0][boff + h * 32 + tq]);
      const float2 kA = *reinterpret_cast<const float2*>(&eks[0][boff + h * 32 + sk]);
      const float2 qB = *reinterpret_cast<const float2*>(&eqs[0][boff + h * 32 + 32 + tq]);
      const float2 kB = *reinterpret_cast<const float2*>(&eks[0][boff + h * 32 + 32 + sk]);
      const float vA = vp[h], vB = vp[h + 1];
      ac0 = __builtin_fmaf(vA, rcpf(__builtin_fmaf(qA.x, kA.x, 1.0f)), ac0);
      ac1 = __builtin_fmaf(vA, rcpf(__builtin_fmaf(qA.x, kA.y, 1.0f)), ac1);
      ac2 = __builtin_fmaf(vA, rcpf(__builtin_fmaf(qA.y, kA.x, 1.0f)), ac2);
      ac3 = __builtin_fmaf(vA, rcpf(__builtin_fmaf(qA.y, kA.y, 1.0f)), ac3);
      ac4 = __builtin_fmaf(vB, rcpf(__builtin_fmaf(qB.x, kB.x, 1.0f)), ac4);
      ac5 = __builtin_fmaf(vB, rcpf(__builtin_fmaf(qB.x, kB.y, 1.0f)), ac5);
      ac6 = __builtin_fmaf(vB, rcpf(__builtin_fmaf(qB.y, kB.x, 1.0f)), ac6);
      ac7 = __builtin_fmaf(vB, rcpf(__builtin_fmaf(qB.y, kB.y, 1.0f)), ac7);
    }
    if (c < 7) {
      asm volatile("s_waitcnt vmcnt(0)" ::: "memory");
      __syncthreads();
    }
  }
#undef STAGE

  // vsum = sum_h v[h]
  float vv = v[lane] + v[lane + 64] + v[lane + 128] + v[lane + 192];
#pragma unroll
  for (int off = 32; off > 0; off >>= 1) vv += __shfl_xor(vv, off, 64);

  float2 row0v = {__builtin_fmaf(-2.0f, ac0 + ac4, vv),
                  __builtin_fmaf(-2.0f, ac1 + ac5, vv)};
  float2 row1v = {__builtin_fmaf(-2.0f, ac2 + ac6, vv),
                  __builtin_fmaf(-2.0f, ac3 + ac7, vv)};
  float* so = Sc + ((size_t)(b * kT + t0 + tq)) * kT + s0 + sk;
  *reinterpret_cast<float2*>(so) = row0v;
  *reinterpret_cast<float2*>(so + kT) = row1v;
}

// ---------------- k3: softmax + weights + context ----------------
// wsc aliases the score buffer: read scores, overwrite with weights.
__global__ __launch_bounds__(512, 4) void attn2_kernel(
    const float* __restrict__ X, float* wsc, float* __restrict__ ctx) {
  __shared__ __align__(16) float sc[4][kT];
  __shared__ float redm[8][4];

  // XCD pinning: b = xcd>>1 -> X[b] (512KB) stays L2-resident per XCD.
  const int id = blockIdx.x;
  const int xcd = id & 7;
  const int b = xcd >> 1;
  const int g = (xcd & 1) * 64 + (id >> 3);  // 0..127
  const int tid = threadIdx.x;
  const int tt0 = 511 - g, tt1 = 256 + g, tt2 = 255 - g, tt3 = g;
  const int tt[4] = {tt0, tt1, tt2, tt3};

  float p[4];
#pragma unroll
  for (int k = 0; k < 4; ++k) {
    const float s = wsc[((size_t)(b * kT + tt[k])) * kT + tid];
    p[k] = (tid <= tt[k]) ? __expf(s) : 0.0f;
    float l = p[k];
#pragma unroll
    for (int off = 32; off > 0; off >>= 1) l += __shfl_xor(l, off, 64);
    if ((tid & 63) == 0) redm[tid >> 6][k] = l;
  }
  __syncthreads();
#pragma unroll
  for (int k = 0; k < 4; ++k) {
    float sum = 0.f;
#pragma unroll
    for (int w = 0; w < 8; ++w) sum += redm[w][k];
    const float wgt = p[k] * rcpf(sum);
    wsc[((size_t)(b * kT + tt[k])) * kT + tid] = wgt;
    sc[k][tid] = wgt;
  }
  __syncthreads();

  // context: halves {rows tt0,tt3} / {rows tt1,tt2}, thread owns h
  const int half = tid >> 8;
  const int h = tid & (kH - 1);
  const int longT = half ? tt1 : tt0;
  const int shortT = half ? tt2 : tt3;
  const float* wL = half ? &sc[1][0] : &sc[0][0];
  const float* wS = half ? &sc[2][0] : &sc[3][0];
  const float* Xb = X + ((size_t)b * kT) * kH + h;

  float aL = 0.f, aS = 0.f;
  int si = 0;
#pragma unroll 8
  for (; si <= shortT; ++si) {
    const float x = Xb[(size_t)si * kH];
    aL = __builtin_fmaf(wL[si], x, aL);
    aS = __builtin_fmaf(wS[si], x, aS);
  }
#pragma unroll 8
  for (; si <= longT; ++si) {
    const float x = Xb[(size_t)si * kH];
    aL = __builtin_fmaf(wL[si], x, aL);
  }
  ctx[(size_t)(b * kT + longT) * kH + h] = aL;
  ctx[(size_t)(b * kT + shortT) * kH + h] = aS;
}

}  // namespace

extern "C" void kernel_launch(void* const* d_in, const int* in_sizes, int n_in,
                              void* d_out, int out_size, void* d_ws,
                              size_t ws_size, hipStream_t stream) {
  const float* X = (const float*)d_in[0];
  const float* W1 = (const float*)d_in[1];
  const float* W2 = (const float*)d_in[2];
  const float* v = (const float*)d_in[3];

  float* ctx = (float*)d_out;                   // [B*T][H]  2 MB
  float* wout = ctx + (size_t)kB * kT * kH;     // [B*T][T]  4 MB
  // scratch inside wout (each stage fully consumed before overwrite):
  float* Wt1 = wout;                            // 256 KB  (k0 -> k1)
  float* Wt2 = wout + (size_t)kH * kH;          // 256 KB  (k0 -> k1)
  float* Sc = wout;                             // 4 MB    (k2 -> k3)
  float* EQt = (float*)d_ws;                    // [B][H][T]  2 MB
  float* EKt = EQt + (size_t)kB * kH * kT;      // [B][H][T]  2 MB

  transpose_w_kernel<<<dim3(8, 8, 2), 256, 0, stream>>>(W1, W2, Wt1, Wt2);
  proj_kernel<<<dim3(kB * kT / 8, 2), 256, 0, stream>>>(X, Wt1, Wt2, EQt, EKt);
  score_kernel<<<544, 256, 0, stream>>>(EQt, EKt, v, Sc);
  attn2_kernel<<<512, 512, 0, stream>>>(X, Sc, ctx);
}

// Round 6
// 73.600 us; speedup vs baseline: 1.7107x; 1.0652x over previous
//
#include <hip/hip_runtime.h>

namespace {

constexpr int kB = 4;
constexpr int kT = 512;
constexpr int kH = 256;

__device__ __forceinline__ float rcpf(float x) {
  return __builtin_amdgcn_rcpf(x);
}

// ---------------- k0: transpose W1,W2 (H x H) into Wt ----------------
__global__ __launch_bounds__(256) void transpose_w_kernel(
    const float* __restrict__ W1, const float* __restrict__ W2,
    float* __restrict__ Wt1, float* __restrict__ Wt2) {
  __shared__ float tile[32][33];
  const float* Win = (blockIdx.z == 0) ? W1 : W2;
  float* Wout = (blockIdx.z == 0) ? Wt1 : Wt2;
  const int jo = blockIdx.x * 32, ho = blockIdx.y * 32;
  const int c = threadIdx.x & 31, r0 = threadIdx.x >> 5;
#pragma unroll
  for (int p = 0; p < 4; ++p)
    tile[r0 + 8 * p][c] = Win[(size_t)(ho + r0 + 8 * p) * kH + jo + c];
  __syncthreads();
#pragma unroll
  for (int p = 0; p < 4; ++p)
    Wout[(size_t)(jo + r0 + 8 * p) * kH + ho + c] = tile[c][r0 + 8 * p];
}

// ---------------- k1: projections, exp, TRANSPOSED layout ----------------
// y==0: EQt[b][h][t] = exp(2*q[t][h]);  y==1: EKt[b][h][s] = exp(2*k[s][h])
// W streamed through LDS with double-buffered global_load_lds (2-phase);
// X rows are block-uniform -> scalar loads (free on the vector pipes).
__global__ __launch_bounds__(256) void proj_kernel(
    const float* __restrict__ X, const float* __restrict__ Wt1,
    const float* __restrict__ Wt2, float* __restrict__ EQt,
    float* __restrict__ EKt) {
  __shared__ __align__(16) float ws[2][8][kH];  // 16 KB

  const int tid = threadIdx.x;  // h
  const int w = tid >> 6, lane = tid & 63;
  const int row0 = blockIdx.x * 8;
  const float* Wt = (blockIdx.y == 0) ? Wt1 : Wt2;
  float* dst = (blockIdx.y == 0) ? EQt : EKt;

  // wave w stages rows u=2w,2w+1 of each 8-row W chunk (1 call = 1 KB row)
  const float* gwA = Wt + (size_t)(2 * w) * kH + lane * 4;
  const float* gwB = gwA + kH;

#define PSTAGE(buf, c)                                                      \
  {                                                                         \
    const size_t go = (size_t)(c) * 8 * kH;                                 \
    __builtin_amdgcn_global_load_lds(                                       \
        (const __attribute__((address_space(1))) void*)(gwA + go),          \
        (__attribute__((address_space(3))) void*)&ws[buf][2 * w][0], 16, 0, \
        0);                                                                 \
    __builtin_amdgcn_global_load_lds(                                       \
        (const __attribute__((address_space(1))) void*)(gwB + go),          \
        (__attribute__((address_space(3))) void*)&ws[buf][2 * w + 1][0], 16, \
        0, 0);                                                              \
  }

  float acc[8];
#pragma unroll
  for (int i = 0; i < 8; ++i) acc[i] = 0.0f;

  PSTAGE(0, 0)
  asm volatile("s_waitcnt vmcnt(0)" ::: "memory");
  __syncthreads();

#pragma unroll 1
  for (int c = 0; c < 32; ++c) {
    if (c < 31) PSTAGE((c + 1) & 1, c + 1)
    const int bf = c & 1;
#pragma unroll
    for (int u = 0; u < 8; ++u) {
      const float wv = ws[bf][u][tid];
#pragma unroll
      for (int i = 0; i < 8; ++i)
        acc[i] = __builtin_fmaf(X[(size_t)(row0 + i) * kH + c * 8 + u], wv,
                                acc[i]);
    }
    if (c < 31) {
      asm volatile("s_waitcnt vmcnt(0)" ::: "memory");
      __syncthreads();
    }
  }
#undef PSTAGE

  const int bb = row0 >> 9, r0 = row0 & (kT - 1);
  float* out = dst + ((size_t)(bb * kH + tid)) * kT + r0;
  float4 lo = {__expf(2.0f * acc[0]), __expf(2.0f * acc[1]),
               __expf(2.0f * acc[2]), __expf(2.0f * acc[3])};
  float4 hi = {__expf(2.0f * acc[4]), __expf(2.0f * acc[5]),
               __expf(2.0f * acc[6]), __expf(2.0f * acc[7])};
  *reinterpret_cast<float4*>(out) = lo;
  *reinterpret_cast<float4*>(out + 4) = hi;
}

// ---------------- k2: LDS double-buffered causal score kernel ----------------
// score[t][s] = vsum - 2 * sum_h v[h] * rcp(EQt[h][t]*EKt[h][s] + 1)
// 32x32 tile per 256-thread block (4 waves x 16x16). 2-phase pipeline.
__global__ __launch_bounds__(256) void score_kernel(
    const float* __restrict__ EQt, const float* __restrict__ EKt,
    const float* __restrict__ v, float* __restrict__ Sc) {
  __shared__ __align__(16) float eqs[2][32 * 32];  // [buf][h*32 + t] 8KB
  __shared__ __align__(16) float eks[2][32 * 32];  // [buf][h*32 + s] 8KB

  const int tid = threadIdx.x;
  const int w = tid >> 6, lane = tid & 63;
  const int blk = blockIdx.x;
  const int xcd = blk & 7;
  const int b = xcd >> 1;
  const int tIdx = (xcd & 1) * 68 + (blk >> 3);  // 0..135 causal 32x32 tiles

  int ti = (int)((__builtin_sqrtf(8.0f * (float)tIdx + 1.0f) - 1.0f) * 0.5f);
  while ((ti + 1) * (ti + 2) / 2 <= tIdx) ++ti;
  while (ti * (ti + 1) / 2 > tIdx) --ti;
  const int si = tIdx - ti * (ti + 1) / 2;
  const int t0 = ti * 32, s0 = si * 32;

  const int hoff = w * 8 + (lane >> 3);
  const int coff = (lane & 7) * 4;
  const float* gq = EQt + ((size_t)(b * kH + hoff) * kT) + t0 + coff;
  const float* gk = EKt + ((size_t)(b * kH + hoff) * kT) + s0 + coff;
  float* lqw = &eqs[0][0] + w * 256;
  float* lkw = &eks[0][0] + w * 256;

#define STAGE(buf, c)                                                        \
  {                                                                          \
    const size_t go = (size_t)(c) * 32 * kT;                                 \
    __builtin_amdgcn_global_load_lds(                                        \
        (const __attribute__((address_space(1))) void*)(gq + go),            \
        (__attribute__((address_space(3))) void*)(lqw + (buf)*1024), 16, 0,  \
        0);                                                                  \
    __builtin_amdgcn_global_load_lds(                                        \
        (const __attribute__((address_space(1))) void*)(gk + go),            \
        (__attribute__((address_space(3))) void*)(lkw + (buf)*1024), 16, 0,  \
        0);                                                                  \
  }

  const int wt = w >> 1, wsx = w & 1;
  const int tq = wt * 16 + 2 * (lane >> 3);
  const int sk = wsx * 16 + 2 * (lane & 7);

  float ac0 = 0.f, ac1 = 0.f, ac2 = 0.f, ac3 = 0.f;
  float ac4 = 0.f, ac5 = 0.f, ac6 = 0.f, ac7 = 0.f;

  STAGE(0, 0)
  asm volatile("s_waitcnt vmcnt(0)" ::: "memory");
  __syncthreads();

#pragma unroll 1
  for (int c = 0; c < 8; ++c) {
    if (c < 7) STAGE((c + 1) & 1, c + 1)
    const int boff = (c & 1) * 1024;
    const float* vp = v + c * 32;
#pragma unroll
    for (int h = 0; h < 32; h += 2) {
      const float2 qA = *reinterpret_cast<const float2*>(&eqs[0][boff + h * 32 + tq]);
      const float2 kA = *reinterpret_cast<const float2*>(&eks[0][boff + h * 32 + sk]);
      const float2 qB = *reinterpret_cast<const float2*>(&eqs[0][boff + h * 32 + 32 + tq]);
      const float2 kB = *reinterpret_cast<const float2*>(&eks[0][boff + h * 32 + 32 + sk]);
      const float vA = vp[h], vB = vp[h + 1];
      ac0 = __builtin_fmaf(vA, rcpf(__builtin_fmaf(qA.x, kA.x, 1.0f)), ac0);
      ac1 = __builtin_fmaf(vA, rcpf(__builtin_fmaf(qA.x, kA.y, 1.0f)), ac1);
      ac2 = __builtin_fmaf(vA, rcpf(__builtin_fmaf(qA.y, kA.x, 1.0f)), ac2);
      ac3 = __builtin_fmaf(vA, rcpf(__builtin_fmaf(qA.y, kA.y, 1.0f)), ac3);
      ac4 = __builtin_fmaf(vB, rcpf(__builtin_fmaf(qB.x, kB.x, 1.0f)), ac4);
      ac5 = __builtin_fmaf(vB, rcpf(__builtin_fmaf(qB.x, kB.y, 1.0f)), ac5);
      ac6 = __builtin_fmaf(vB, rcpf(__builtin_fmaf(qB.y, kB.x, 1.0f)), ac6);
      ac7 = __builtin_fmaf(vB, rcpf(__builtin_fmaf(qB.y, kB.y, 1.0f)), ac7);
    }
    if (c < 7) {
      asm volatile("s_waitcnt vmcnt(0)" ::: "memory");
      __syncthreads();
    }
  }
#undef STAGE

  float vv = v[lane] + v[lane + 64] + v[lane + 128] + v[lane + 192];
#pragma unroll
  for (int off = 32; off > 0; off >>= 1) vv += __shfl_xor(vv, off, 64);

  float2 row0v = {__builtin_fmaf(-2.0f, ac0 + ac4, vv),
                  __builtin_fmaf(-2.0f, ac1 + ac5, vv)};
  float2 row1v = {__builtin_fmaf(-2.0f, ac2 + ac6, vv),
                  __builtin_fmaf(-2.0f, ac3 + ac7, vv)};
  float* so = Sc + ((size_t)(b * kT + t0 + tq)) * kT + s0 + sk;
  *reinterpret_cast<float2*>(so) = row0v;
  *reinterpret_cast<float2*>(so + kT) = row1v;
}

// ---------------- k3: softmax + weights + context (8 rows/block) ----------------
// wsc aliases the score buffer: read scores, overwrite with weights.
// Phase 1: wave w does softmax of row row0+w. Phase 2: full-s context
// (weights are exact zeros above diagonal), s-split in halves. Phase 3: combine.
__global__ __launch_bounds__(512) void attn2_kernel(
    const float* __restrict__ X, float* wsc, float* __restrict__ ctx) {
  __shared__ float wls[8][kT + 8];   // weights, padded rows
  __shared__ float pc[2][8][kH];     // partial context [half][r][h]

  const int id = blockIdx.x;
  const int xcd = id & 7;
  const int b = xcd >> 1;                      // XCD-pinned batch
  const int sub = (xcd & 1) * 32 + (id >> 3);  // 0..63
  const int row0 = sub * 8;
  const int tid = threadIdx.x;
  const int w = tid >> 6, lane = tid & 63;

  // ---- softmax: wave w -> row t = row0 + w ----
  const int t = row0 + w;
  float* srow = wsc + ((size_t)(b * kT + t)) * kT;
  const int sbase8 = lane * 8;
  float4 s4a = *reinterpret_cast<const float4*>(srow + sbase8);
  float4 s4b = *reinterpret_cast<const float4*>(srow + sbase8 + 4);
  float p[8];
  p[0] = (sbase8 + 0 <= t) ? __expf(s4a.x) : 0.f;
  p[1] = (sbase8 + 1 <= t) ? __expf(s4a.y) : 0.f;
  p[2] = (sbase8 + 2 <= t) ? __expf(s4a.z) : 0.f;
  p[3] = (sbase8 + 3 <= t) ? __expf(s4a.w) : 0.f;
  p[4] = (sbase8 + 4 <= t) ? __expf(s4b.x) : 0.f;
  p[5] = (sbase8 + 5 <= t) ? __expf(s4b.y) : 0.f;
  p[6] = (sbase8 + 6 <= t) ? __expf(s4b.z) : 0.f;
  p[7] = (sbase8 + 7 <= t) ? __expf(s4b.w) : 0.f;
  float l = ((p[0] + p[1]) + (p[2] + p[3])) + ((p[4] + p[5]) + (p[6] + p[7]));
#pragma unroll
  for (int off = 32; off > 0; off >>= 1) l += __shfl_xor(l, off, 64);
  const float rs = rcpf(l);
#pragma unroll
  for (int j = 0; j < 8; ++j) p[j] *= rs;
  float4 o4a = {p[0], p[1], p[2], p[3]};
  float4 o4b = {p[4], p[5], p[6], p[7]};
  *reinterpret_cast<float4*>(srow + sbase8) = o4a;
  *reinterpret_cast<float4*>(srow + sbase8 + 4) = o4b;
#pragma unroll
  for (int j = 0; j < 8; ++j) wls[w][sbase8 + j] = p[j];
  __syncthreads();

  // ---- context: thread (h, half); full s-range (zeros mask the future) ----
  const int h = tid & (kH - 1);
  const int half = tid >> 8;
  const float* Xb = X + ((size_t)b * kT) * kH + h;
  float acc[8];
#pragma unroll
  for (int r = 0; r < 8; ++r) acc[r] = 0.f;
  const int sb = half * 256;
#pragma unroll 4
  for (int so = 0; so < 256; ++so) {
    const int s = sb + so;
    const float x = Xb[(size_t)s * kH];
#pragma unroll
    for (int r = 0; r < 8; ++r)
      acc[r] = __builtin_fmaf(wls[r][s], x, acc[r]);
  }
#pragma unroll
  for (int r = 0; r < 8; ++r) pc[half][r][h] = acc[r];
  __syncthreads();

  // ---- combine halves: 4 outputs per thread ----
#pragma unroll
  for (int q = 0; q < 4; ++q) {
    const int idx = q * 512 + tid;       // 0..2047
    const int r = idx >> 8, hh = idx & (kH - 1);
    ctx[((size_t)(b * kT + row0 + r)) * kH + hh] = pc[0][r][hh] + pc[1][r][hh];
  }
}

}  // namespace

extern "C" void kernel_launch(void* const* d_in, const int* in_sizes, int n_in,
                              void* d_out, int out_size, void* d_ws,
                              size_t ws_size, hipStream_t stream) {
  const float* X = (const float*)d_in[0];
  const float* W1 = (const float*)d_in[1];
  const float* W2 = (const float*)d_in[2];
  const float* v = (const float*)d_in[3];

  float* ctx = (float*)d_out;                   // [B*T][H]  2 MB
  float* wout = ctx + (size_t)kB * kT * kH;     // [B*T][T]  4 MB
  // scratch inside wout (each stage fully consumed before overwrite):
  float* Wt1 = wout;                            // 256 KB  (k0 -> k1)
  float* Wt2 = wout + (size_t)kH * kH;          // 256 KB  (k0 -> k1)
  float* Sc = wout;                             // 4 MB    (k2 -> k3)
  float* EQt = (float*)d_ws;                    // [B][H][T]  2 MB
  float* EKt = EQt + (size_t)kB * kH * kT;      // [B][H][T]  2 MB

  transpose_w_kernel<<<dim3(8, 8, 2), 256, 0, stream>>>(W1, W2, Wt1, Wt2);
  proj_kernel<<<dim3(kB * kT / 8, 2), 256, 0, stream>>>(X, Wt1, Wt2, EQt, EKt);
  score_kernel<<<544, 256, 0, stream>>>(EQt, EKt, v, Sc);
  attn2_kernel<<<256, 512, 0, stream>>>(X, Sc, ctx);
}

// Round 7
// 68.817 us; speedup vs baseline: 1.8296x; 1.0695x over previous
//
#include <hip/hip_runtime.h>

namespace {

constexpr int kB = 4;
constexpr int kT = 512;
constexpr int kH = 256;

__device__ __forceinline__ float rcpf(float x) {
  return __builtin_amdgcn_rcpf(x);
}

// ---------------- k0: transpose W1,W2 (H x H) into Wt ----------------
__global__ __launch_bounds__(256) void transpose_w_kernel(
    const float* __restrict__ W1, const float* __restrict__ W2,
    float* __restrict__ Wt1, float* __restrict__ Wt2) {
  __shared__ float tile[32][33];
  const float* Win = (blockIdx.z == 0) ? W1 : W2;
  float* Wout = (blockIdx.z == 0) ? Wt1 : Wt2;
  const int jo = blockIdx.x * 32, ho = blockIdx.y * 32;
  const int c = threadIdx.x & 31, r0 = threadIdx.x >> 5;
#pragma unroll
  for (int p = 0; p < 4; ++p)
    tile[r0 + 8 * p][c] = Win[(size_t)(ho + r0 + 8 * p) * kH + jo + c];
  __syncthreads();
#pragma unroll
  for (int p = 0; p < 4; ++p)
    Wout[(size_t)(jo + r0 + 8 * p) * kH + ho + c] = tile[c][r0 + 8 * p];
}

// ---------------- k1: projections, exp, TRANSPOSED layout ----------------
// y==0: EQt[b][h][t] = exp(2*q[t][h]);  y==1: EKt[b][h][s] = exp(2*k[s][h])
// W streamed through a 4-deep LDS ring: counted vmcnt + raw s_barrier
// (one barrier per chunk, never drain to 0 mid-loop).
__global__ __launch_bounds__(256) void proj_kernel(
    const float* __restrict__ X, const float* __restrict__ Wt1,
    const float* __restrict__ Wt2, float* __restrict__ EQt,
    float* __restrict__ EKt) {
  __shared__ __align__(16) float ws[4][8][kH];  // 32 KB ring

  const int tid = threadIdx.x;  // h
  const int w = tid >> 6, lane = tid & 63;
  const int row0 = blockIdx.x * 8;
  const float* Wt = (blockIdx.y == 0) ? Wt1 : Wt2;
  float* dst = (blockIdx.y == 0) ? EQt : EKt;

  // wave w stages rows u=2w,2w+1 of each 8-row W chunk (1 call = 1 KB row)
  const float* gwA = Wt + (size_t)(2 * w) * kH + lane * 4;
  const float* gwB = gwA + kH;

#define PSTAGE(buf, c)                                                       \
  {                                                                          \
    const size_t go = (size_t)(c) * 8 * kH;                                  \
    __builtin_amdgcn_global_load_lds(                                        \
        (const __attribute__((address_space(1))) void*)(gwA + go),           \
        (__attribute__((address_space(3))) void*)&ws[buf][2 * w][0], 16, 0,  \
        0);                                                                  \
    __builtin_amdgcn_global_load_lds(                                        \
        (const __attribute__((address_space(1))) void*)(gwB + go),           \
        (__attribute__((address_space(3))) void*)&ws[buf][2 * w + 1][0], 16, \
        0, 0);                                                               \
  }

  float acc[8];
#pragma unroll
  for (int i = 0; i < 8; ++i) acc[i] = 0.0f;

  PSTAGE(0, 0)
  PSTAGE(1, 1)
  PSTAGE(2, 2)

#pragma unroll 1
  for (int c = 0; c < 32; ++c) {
    // chunk c's 2 loads are older than the (at most 4) loads of c+1,c+2
    if (c <= 29) {
      asm volatile("s_waitcnt vmcnt(4)" ::: "memory");
    } else if (c == 30) {
      asm volatile("s_waitcnt vmcnt(2)" ::: "memory");
    } else {
      asm volatile("s_waitcnt vmcnt(0)" ::: "memory");
    }
    __builtin_amdgcn_s_barrier();
    __builtin_amdgcn_sched_barrier(0);
    if (c <= 28) PSTAGE((c + 3) & 3, c + 3)
    const int bf = c & 3;
#pragma unroll
    for (int u = 0; u < 8; ++u) {
      const float wv = ws[bf][u][tid];
#pragma unroll
      for (int i = 0; i < 8; ++i)
        acc[i] = __builtin_fmaf(X[(size_t)(row0 + i) * kH + c * 8 + u], wv,
                                acc[i]);
    }
  }
#undef PSTAGE

  const int bb = row0 >> 9, r0 = row0 & (kT - 1);
  float* out = dst + ((size_t)(bb * kH + tid)) * kT + r0;
  float4 lo = {__expf(2.0f * acc[0]), __expf(2.0f * acc[1]),
               __expf(2.0f * acc[2]), __expf(2.0f * acc[3])};
  float4 hi = {__expf(2.0f * acc[4]), __expf(2.0f * acc[5]),
               __expf(2.0f * acc[6]), __expf(2.0f * acc[7])};
  *reinterpret_cast<float4*>(out) = lo;
  *reinterpret_cast<float4*>(out + 4) = hi;
}

// ---------------- k2: causal score kernel, 4-deep LDS ring ----------------
// score[t][s] = vsum - 2 * sum_h v[h] * rcp(EQt[h][t]*EKt[h][s] + 1)
// 32x32 tile per 256-thread block (4 waves x 16x16); counted-vmcnt pipeline.
__global__ __launch_bounds__(256) void score_kernel(
    const float* __restrict__ EQt, const float* __restrict__ EKt,
    const float* __restrict__ v, float* __restrict__ Sc) {
  __shared__ __align__(16) float eqs[4][32 * 32];  // [buf][h*32 + t] 16KB
  __shared__ __align__(16) float eks[4][32 * 32];  // [buf][h*32 + s] 16KB

  const int tid = threadIdx.x;
  const int w = tid >> 6, lane = tid & 63;
  const int blk = blockIdx.x;
  const int xcd = blk & 7;
  const int b = xcd >> 1;  // XCD-pinned batch
  const int tIdx = (xcd & 1) * 68 + (blk >> 3);  // 0..135 causal 32x32 tiles

  int ti = (int)((__builtin_sqrtf(8.0f * (float)tIdx + 1.0f) - 1.0f) * 0.5f);
  while ((ti + 1) * (ti + 2) / 2 <= tIdx) ++ti;
  while (ti * (ti + 1) / 2 > tIdx) --ti;
  const int si = tIdx - ti * (ti + 1) / 2;
  const int t0 = ti * 32, s0 = si * 32;

  const int hoff = w * 8 + (lane >> 3);
  const int coff = (lane & 7) * 4;
  const float* gq = EQt + ((size_t)(b * kH + hoff) * kT) + t0 + coff;
  const float* gk = EKt + ((size_t)(b * kH + hoff) * kT) + s0 + coff;
  float* lqw = &eqs[0][0] + w * 256;  // wave-uniform LDS dest base
  float* lkw = &eks[0][0] + w * 256;

#define STAGE(buf, c)                                                        \
  {                                                                          \
    const size_t go = (size_t)(c) * 32 * kT;                                 \
    __builtin_amdgcn_global_load_lds(                                        \
        (const __attribute__((address_space(1))) void*)(gq + go),            \
        (__attribute__((address_space(3))) void*)(lqw + (buf)*1024), 16, 0,  \
        0);                                                                  \
    __builtin_amdgcn_global_load_lds(                                        \
        (const __attribute__((address_space(1))) void*)(gk + go),            \
        (__attribute__((address_space(3))) void*)(lkw + (buf)*1024), 16, 0,  \
        0);                                                                  \
  }

  const int wt = w >> 1, wsx = w & 1;
  const int tq = wt * 16 + 2 * (lane >> 3);
  const int sk = wsx * 16 + 2 * (lane & 7);

  float ac0 = 0.f, ac1 = 0.f, ac2 = 0.f, ac3 = 0.f;
  float ac4 = 0.f, ac5 = 0.f, ac6 = 0.f, ac7 = 0.f;

  STAGE(0, 0)
  STAGE(1, 1)
  STAGE(2, 2)

#pragma unroll 1
  for (int c = 0; c < 8; ++c) {
    if (c <= 5) {
      asm volatile("s_waitcnt vmcnt(4)" ::: "memory");
    } else if (c == 6) {
      asm volatile("s_waitcnt vmcnt(2)" ::: "memory");
    } else {
      asm volatile("s_waitcnt vmcnt(0)" ::: "memory");
    }
    __builtin_amdgcn_s_barrier();
    __builtin_amdgcn_sched_barrier(0);
    if (c <= 4) STAGE((c + 3) & 3, c + 3)
    const int boff = (c & 3) * 1024;
    const float* vp = v + c * 32;  // uniform -> s_load
#pragma unroll
    for (int h = 0; h < 32; h += 2) {
      const float2 qA = *reinterpret_cast<const float2*>(&eqs[0][boff + h * 32 + tq]);
      const float2 kA = *reinterpret_cast<const float2*>(&eks[0][boff + h * 32 + sk]);
      const float2 qB = *reinterpret_cast<const float2*>(&eqs[0][boff + h * 32 + 32 + tq]);
      const float2 kB = *reinterpret_cast<const float2*>(&eks[0][boff + h * 32 + 32 + sk]);
      const float vA = vp[h], vB = vp[h + 1];
      ac0 = __builtin_fmaf(vA, rcpf(__builtin_fmaf(qA.x, kA.x, 1.0f)), ac0);
      ac1 = __builtin_fmaf(vA, rcpf(__builtin_fmaf(qA.x, kA.y, 1.0f)), ac1);
      ac2 = __builtin_fmaf(vA, rcpf(__builtin_fmaf(qA.y, kA.x, 1.0f)), ac2);
      ac3 = __builtin_fmaf(vA, rcpf(__builtin_fmaf(qA.y, kA.y, 1.0f)), ac3);
      ac4 = __builtin_fmaf(vB, rcpf(__builtin_fmaf(qB.x, kB.x, 1.0f)), ac4);
      ac5 = __builtin_fmaf(vB, rcpf(__builtin_fmaf(qB.x, kB.y, 1.0f)), ac5);
      ac6 = __builtin_fmaf(vB, rcpf(__builtin_fmaf(qB.y, kB.x, 1.0f)), ac6);
      ac7 = __builtin_fmaf(vB, rcpf(__builtin_fmaf(qB.y, kB.y, 1.0f)), ac7);
    }
  }
#undef STAGE

  float vv = v[lane] + v[lane + 64] + v[lane + 128] + v[lane + 192];
#pragma unroll
  for (int off = 32; off > 0; off >>= 1) vv += __shfl_xor(vv, off, 64);

  float2 row0v = {__builtin_fmaf(-2.0f, ac0 + ac4, vv),
                  __builtin_fmaf(-2.0f, ac1 + ac5, vv)};
  float2 row1v = {__builtin_fmaf(-2.0f, ac2 + ac6, vv),
                  __builtin_fmaf(-2.0f, ac3 + ac7, vv)};
  float* so = Sc + ((size_t)(b * kT + t0 + tq)) * kT + s0 + sk;
  *reinterpret_cast<float2*>(so) = row0v;
  *reinterpret_cast<float2*>(so + kT) = row1v;
}

// ---------------- k3: softmax + weights + context (8 rows/block) ----------------
// wsc aliases the score buffer: read scores, overwrite with weights.
__global__ __launch_bounds__(512) void attn2_kernel(
    const float* __restrict__ X, float* wsc, float* __restrict__ ctx) {
  __shared__ float wls[8][kT + 8];   // weights, padded rows
  __shared__ float pc[2][8][kH];     // partial context [half][r][h]

  const int id = blockIdx.x;
  const int xcd = id & 7;
  const int b = xcd >> 1;                      // XCD-pinned batch
  const int sub = (xcd & 1) * 32 + (id >> 3);  // 0..63
  const int row0 = sub * 8;
  const int tid = threadIdx.x;
  const int w = tid >> 6, lane = tid & 63;

  // ---- softmax: wave w -> row t = row0 + w ----
  const int t = row0 + w;
  float* srow = wsc + ((size_t)(b * kT + t)) * kT;
  const int sbase8 = lane * 8;
  float4 s4a = *reinterpret_cast<const float4*>(srow + sbase8);
  float4 s4b = *reinterpret_cast<const float4*>(srow + sbase8 + 4);
  float p[8];
  p[0] = (sbase8 + 0 <= t) ? __expf(s4a.x) : 0.f;
  p[1] = (sbase8 + 1 <= t) ? __expf(s4a.y) : 0.f;
  p[2] = (sbase8 + 2 <= t) ? __expf(s4a.z) : 0.f;
  p[3] = (sbase8 + 3 <= t) ? __expf(s4a.w) : 0.f;
  p[4] = (sbase8 + 4 <= t) ? __expf(s4b.x) : 0.f;
  p[5] = (sbase8 + 5 <= t) ? __expf(s4b.y) : 0.f;
  p[6] = (sbase8 + 6 <= t) ? __expf(s4b.z) : 0.f;
  p[7] = (sbase8 + 7 <= t) ? __expf(s4b.w) : 0.f;
  float l = ((p[0] + p[1]) + (p[2] + p[3])) + ((p[4] + p[5]) + (p[6] + p[7]));
#pragma unroll
  for (int off = 32; off > 0; off >>= 1) l += __shfl_xor(l, off, 64);
  const float rs = rcpf(l);
#pragma unroll
  for (int j = 0; j < 8; ++j) p[j] *= rs;
  float4 o4a = {p[0], p[1], p[2], p[3]};
  float4 o4b = {p[4], p[5], p[6], p[7]};
  *reinterpret_cast<float4*>(srow + sbase8) = o4a;
  *reinterpret_cast<float4*>(srow + sbase8 + 4) = o4b;
#pragma unroll
  for (int j = 0; j < 8; ++j) wls[w][sbase8 + j] = p[j];
  __syncthreads();

  // ---- context: thread (h, half); full s-range (zeros mask the future) ----
  const int h = tid & (kH - 1);
  const int half = tid >> 8;
  const float* Xb = X + ((size_t)b * kT) * kH + h;
  float acc[8];
#pragma unroll
  for (int r = 0; r < 8; ++r) acc[r] = 0.f;
  const int sb = half * 256;
#pragma unroll 4
  for (int so = 0; so < 256; ++so) {
    const int s = sb + so;
    const float x = Xb[(size_t)s * kH];
#pragma unroll
    for (int r = 0; r < 8; ++r)
      acc[r] = __builtin_fmaf(wls[r][s], x, acc[r]);
  }
#pragma unroll
  for (int r = 0; r < 8; ++r) pc[half][r][h] = acc[r];
  __syncthreads();

  // ---- combine halves: 4 outputs per thread ----
#pragma unroll
  for (int q = 0; q < 4; ++q) {
    const int idx = q * 512 + tid;       // 0..2047
    const int r = idx >> 8, hh = idx & (kH - 1);
    ctx[((size_t)(b * kT + row0 + r)) * kH + hh] = pc[0][r][hh] + pc[1][r][hh];
  }
}

}  // namespace

extern "C" void kernel_launch(void* const* d_in, const int* in_sizes, int n_in,
                              void* d_out, int out_size, void* d_ws,
                              size_t ws_size, hipStream_t stream) {
  const float* X = (const float*)d_in[0];
  const float* W1 = (const float*)d_in[1];
  const float* W2 = (const float*)d_in[2];
  const float* v = (const float*)d_in[3];

  float* ctx = (float*)d_out;                   // [B*T][H]  2 MB
  float* wout = ctx + (size_t)kB * kT * kH;     // [B*T][T]  4 MB
  // scratch inside wout (each stage fully consumed before overwrite):
  float* Wt1 = wout;                            // 256 KB  (k0 -> k1)
  float* Wt2 = wout + (size_t)kH * kH;          // 256 KB  (k0 -> k1)
  float* Sc = wout;                             // 4 MB    (k2 -> k3)
  float* EQt = (float*)d_ws;                    // [B][H][T]  2 MB
  float* EKt = EQt + (size_t)kB * kH * kT;      // [B][H][T]  2 MB

  transpose_w_kernel<<<dim3(8, 8, 2), 256, 0, stream>>>(W1, W2, Wt1, Wt2);
  proj_kernel<<<dim3(kB * kT / 8, 2), 256, 0, stream>>>(X, Wt1, Wt2, EQt, EKt);
  score_kernel<<<544, 256, 0, stream>>>(EQt, EKt, v, Sc);
  attn2_kernel<<<256, 512, 0, stream>>>(X, Sc, ctx);
}